// Round 1
// baseline (536.779 us; speedup 1.0000x reference)
//
#include <hip/hip_runtime.h>
#include <hip/hip_bf16.h>

#define NN 50000
#define NE 800000
#define NT 2000000

typedef __attribute__((ext_vector_type(8))) short short8;
typedef __attribute__((ext_vector_type(4))) float f32x4;

__device__ __forceinline__ short bf16_of(float f) {
    unsigned u = __float_as_uint(f);
    unsigned r = (u + 0x7fffu + ((u >> 16) & 1u)) >> 16;
    return (short)r;
}

__device__ __forceinline__ float softplus_f(float x) {
    float t = __expf(-fabsf(x));
    return fmaxf(x, 0.0f) + __logf(1.0f + t);
}

__device__ __forceinline__ short8 to_bf8(float4 u, float4 v) {
    short8 r;
    r[0] = bf16_of(u.x); r[1] = bf16_of(u.y); r[2] = bf16_of(u.z); r[3] = bf16_of(u.w);
    r[4] = bf16_of(v.x); r[5] = bf16_of(v.y); r[6] = bf16_of(v.z); r[7] = bf16_of(v.w);
    return r;
}

__device__ __forceinline__ float dcomp(float4 d, int a) {
    return a == 0 ? d.x : (a == 1 ? d.y : d.z);
}

struct MlpW {
    short8 wb[2][2][4];   // [layer][ktile][ntile] B-frags of W (bf16)
    float scale[2][4];    // BN scale per (layer, ntile) for col nt*16 + (lane&15)
    float bias[2][4];     // fused linear-bias + BN shift
    float wo[4];
    float bo;
};

__device__ __forceinline__ void load_weights(
    const float* __restrict__ W, const float* __restrict__ b,
    const float* __restrict__ g, const float* __restrict__ bt,
    const float* __restrict__ m, const float* __restrict__ v,
    const float* __restrict__ Wo, const float* __restrict__ bo, MlpW& w) {
    const int lane = threadIdx.x & 63;
    const int grp = lane >> 4, c = lane & 15;
#pragma unroll
    for (int l = 0; l < 2; ++l) {
#pragma unroll
        for (int kt = 0; kt < 2; ++kt)
#pragma unroll
            for (int nt = 0; nt < 4; ++nt) {
                short8 f;
#pragma unroll
                for (int i = 0; i < 8; ++i)
                    f[i] = bf16_of(W[l * 4096 + (kt * 32 + grp * 8 + i) * 64 + nt * 16 + c]);
                w.wb[l][kt][nt] = f;
            }
#pragma unroll
        for (int nt = 0; nt < 4; ++nt) {
            int j = nt * 16 + c;
            float s = g[l * 64 + j] * rsqrtf(v[l * 64 + j] + 1e-5f);
            w.scale[l][nt] = s;
            w.bias[l][nt] = (b[l * 64 + j] - m[l * 64 + j]) * s + bt[l * 64 + j];
        }
    }
#pragma unroll
    for (int nt = 0; nt < 4; ++nt) w.wo[nt] = Wo[nt * 16 + c];
    w.bo = bo[0];
}

// Evaluate MLP on 16 rows (one wave). out_s[r] = scalar for local row (lane>>4)*4+r.
__device__ __forceinline__ void mlp_tile(const float* __restrict__ xrow, const MlpW& w,
                                         unsigned short* lds, float out_s[4]) {
    const int lane = threadIdx.x & 63;
    const int grp = lane >> 4, c = lane & 15;
    // A-frags: lane holds row c, k = grp*8 + i (and +32)
    const float4* rp = (const float4*)(xrow + c * 64 + grp * 8);
    float4 x0 = rp[0], x1 = rp[1], x2 = rp[8], x3 = rp[9];
    short8 a0 = to_bf8(x0, x1), a1 = to_bf8(x2, x3);
    f32x4 acc[4];
#pragma unroll
    for (int nt = 0; nt < 4; ++nt) {
        f32x4 z = {0.f, 0.f, 0.f, 0.f};
        z = __builtin_amdgcn_mfma_f32_16x16x32_bf16(a0, w.wb[0][0][nt], z, 0, 0, 0);
        z = __builtin_amdgcn_mfma_f32_16x16x32_bf16(a1, w.wb[0][1][nt], z, 0, 0, 0);
        acc[nt] = z;
    }
    // BN + softplus -> bf16 -> LDS (swizzled [16 rows][64 cols] bf16)
#pragma unroll
    for (int nt = 0; nt < 4; ++nt)
#pragma unroll
        for (int r = 0; r < 4; ++r) {
            float y = softplus_f(acc[nt][r] * w.scale[0][nt] + w.bias[0][nt]);
            int row = grp * 4 + r;
            int byte = (row * 128 + (nt * 16 + c) * 2) ^ ((row & 7) << 4);
            *(unsigned short*)((char*)lds + byte) = (unsigned short)bf16_of(y);
        }
    // layer-2 A-frags from LDS (row = c, k = grp*8 + i)
    short8 b0 = *(const short8*)((char*)lds + ((c * 128 + grp * 16) ^ ((c & 7) << 4)));
    short8 b1 = *(const short8*)((char*)lds + ((c * 128 + 64 + grp * 16) ^ ((c & 7) << 4)));
    f32x4 acc2[4];
#pragma unroll
    for (int nt = 0; nt < 4; ++nt) {
        f32x4 z = {0.f, 0.f, 0.f, 0.f};
        z = __builtin_amdgcn_mfma_f32_16x16x32_bf16(b0, w.wb[1][0][nt], z, 0, 0, 0);
        z = __builtin_amdgcn_mfma_f32_16x16x32_bf16(b1, w.wb[1][1][nt], z, 0, 0, 0);
        acc2[nt] = z;
    }
    float p[4] = {0.f, 0.f, 0.f, 0.f};
#pragma unroll
    for (int nt = 0; nt < 4; ++nt)
#pragma unroll
        for (int r = 0; r < 4; ++r) {
            float y = softplus_f(acc2[nt][r] * w.scale[1][nt] + w.bias[1][nt]);
            p[r] = fmaf(y, w.wo[nt], p[r]);
        }
#pragma unroll
    for (int msk = 1; msk < 16; msk <<= 1)
#pragma unroll
        for (int r = 0; r < 4; ++r) p[r] += __shfl_xor(p[r], msk);
#pragma unroll
    for (int r = 0; r < 4; ++r) out_s[r] = p[r] + w.bo;
}

__global__ void geom_kernel(const float* __restrict__ pos,
                            const float* __restrict__ nbr_shift,
                            const int* __restrict__ edge_index,
                            float4* __restrict__ dirlen) {
    int e = blockIdx.x * blockDim.x + threadIdx.x;
    if (e >= NE) return;
    int j = edge_index[e];
    int i = edge_index[NE + e];
    // replicate numpy fp32 op order exactly (cutoff boundary sensitivity)
    float dx = __fsub_rn(__fadd_rn(pos[i * 3 + 0], nbr_shift[e * 3 + 0]), pos[j * 3 + 0]);
    float dy = __fsub_rn(__fadd_rn(pos[i * 3 + 1], nbr_shift[e * 3 + 1]), pos[j * 3 + 1]);
    float dz = __fsub_rn(__fadd_rn(pos[i * 3 + 2], nbr_shift[e * 3 + 2]), pos[j * 3 + 2]);
    float l2 = __fadd_rn(__fadd_rn(__fmul_rn(dx, dx), __fmul_rn(dy, dy)), __fmul_rn(dz, dz));
    float len = __fsqrt_rn(l2);
    float4 o;
    o.x = __fdiv_rn(dx, len);
    o.y = __fdiv_rn(dy, len);
    o.z = __fdiv_rn(dz, len);
    o.w = len;
    dirlen[e] = o;
}

__global__ __launch_bounds__(256) void edge_kernel(
    const float* __restrict__ edge_attr, const float* __restrict__ eW,
    const float* __restrict__ eb, const float* __restrict__ eg,
    const float* __restrict__ ebeta, const float* __restrict__ em,
    const float* __restrict__ ev, const float* __restrict__ eWo,
    const float* __restrict__ ebo, const int* __restrict__ edge_index,
    const float4* __restrict__ dirlen, float* __restrict__ out) {
    __shared__ __align__(16) unsigned short lds_t[4][1024];
    __shared__ float lds_s[4][16];
    const int wave = threadIdx.x >> 6;
    const int lane = threadIdx.x & 63;
    MlpW w;
    load_weights(eW, eb, eg, ebeta, em, ev, eWo, ebo, w);
    const int gwave = blockIdx.x * 4 + wave;
    const int nwaves = gridDim.x * 4;
    const int ntiles = NE / 16;
    for (int tile = gwave; tile < ntiles; tile += nwaves) {
        float s[4];
        mlp_tile(edge_attr + (size_t)tile * 1024, w, &lds_t[wave][0], s);
        if ((lane & 15) == 0) {
#pragma unroll
            for (int r = 0; r < 4; ++r) lds_s[wave][(lane >> 4) * 4 + r] = s[r];
        }
#pragma unroll
        for (int p = 0; p < 3; ++p) {
            int idx = p * 64 + lane;
            if (idx < 144) {
                int el = idx / 9;
                int comp = idx - el * 9;
                int a = comp / 3, bb = comp - a * 3;
                int eg_ = tile * 16 + el;
                float4 d = dirlen[eg_];
                float val = lds_s[wave][el] * dcomp(d, a) * dcomp(d, bb);
                int tgt = edge_index[NE + eg_];
                atomicAdd(&out[tgt * 9 + comp], val);
            }
        }
    }
}

__global__ __launch_bounds__(256) void trip_kernel(
    const float* __restrict__ trip_attr, const float* __restrict__ tW,
    const float* __restrict__ tb, const float* __restrict__ tg,
    const float* __restrict__ tbeta, const float* __restrict__ tm,
    const float* __restrict__ tv, const float* __restrict__ tWo,
    const float* __restrict__ tbo, const int* __restrict__ idx_j,
    const int* __restrict__ idx_kj, const int* __restrict__ idx_ji,
    const float4* __restrict__ dirlen, float* __restrict__ out) {
    __shared__ __align__(16) unsigned short lds_t[4][1024];
    __shared__ float lds_s[4][16];
    const int wave = threadIdx.x >> 6;
    const int lane = threadIdx.x & 63;
    MlpW w;
    load_weights(tW, tb, tg, tbeta, tm, tv, tWo, tbo, w);
    const int gwave = blockIdx.x * 4 + wave;
    const int nwaves = gridDim.x * 4;
    const int ntiles = NT / 16;
    for (int tile = gwave; tile < ntiles; tile += nwaves) {
        float s[4];
        mlp_tile(trip_attr + (size_t)tile * 1024, w, &lds_t[wave][0], s);
        if ((lane & 15) == 0) {
#pragma unroll
            for (int r = 0; r < 4; ++r) lds_s[wave][(lane >> 4) * 4 + r] = s[r];
        }
#pragma unroll
        for (int p = 0; p < 3; ++p) {
            int idx = p * 64 + lane;
            if (idx < 144) {
                int el = idx / 9;
                int comp = idx - el * 9;
                int a = comp / 3, bb = comp - a * 3;
                int t = tile * 16 + el;
                int kj = idx_kj[t], ji = idx_ji[t];
                float4 dk = dirlen[kj];
                float4 dj = dirlen[ji];
                if (dk.w < 6.0f && dj.w < 6.0f) {
                    float val = lds_s[wave][el] * dcomp(dk, a) * dcomp(dj, bb);
                    atomicAdd(&out[idx_j[t] * 9 + comp], val);
                }
            }
        }
    }
}

extern "C" void kernel_launch(void* const* d_in, const int* in_sizes, int n_in,
                              void* d_out, int out_size, void* d_ws, size_t ws_size,
                              hipStream_t stream) {
    const float* pos       = (const float*)d_in[0];
    const float* nbr_shift = (const float*)d_in[1];
    const float* edge_attr = (const float*)d_in[2];
    const float* trip_attr = (const float*)d_in[3];
    const float* eW    = (const float*)d_in[4];
    const float* eb    = (const float*)d_in[5];
    const float* eg    = (const float*)d_in[6];
    const float* ebeta = (const float*)d_in[7];
    const float* em    = (const float*)d_in[8];
    const float* ev    = (const float*)d_in[9];
    const float* eWo   = (const float*)d_in[10];
    const float* ebo   = (const float*)d_in[11];
    const float* tW    = (const float*)d_in[12];
    const float* tb    = (const float*)d_in[13];
    const float* tg    = (const float*)d_in[14];
    const float* tbeta = (const float*)d_in[15];
    const float* tm    = (const float*)d_in[16];
    const float* tv    = (const float*)d_in[17];
    const float* tWo   = (const float*)d_in[18];
    const float* tbo   = (const float*)d_in[19];
    const int* edge_index = (const int*)d_in[20];
    const int* idx_j      = (const int*)d_in[21];
    const int* idx_kj     = (const int*)d_in[22];
    const int* idx_ji     = (const int*)d_in[23];
    float* out = (float*)d_out;
    float4* dirlen = (float4*)d_ws;

    hipMemsetAsync(d_out, 0, (size_t)out_size * sizeof(float), stream);
    geom_kernel<<<(NE + 255) / 256, 256, 0, stream>>>(pos, nbr_shift, edge_index, dirlen);
    edge_kernel<<<1024, 256, 0, stream>>>(edge_attr, eW, eb, eg, ebeta, em, ev, eWo, ebo,
                                          edge_index, dirlen, out);
    trip_kernel<<<2048, 256, 0, stream>>>(trip_attr, tW, tb, tg, tbeta, tm, tv, tWo, tbo,
                                          idx_j, idx_kj, idx_ji, dirlen, out);
}